// Round 10
// baseline (240.741 us; speedup 1.0000x reference)
//
#include <hip/hip_runtime.h>
#include <hip/hip_fp16.h>

#define N_NODES 100000
#define N_EDGES 3200000
#define ET (N_EDGES + N_NODES)   // edges + self-loops
#define IN_F 128
#define HID_F 64
#define OUT_F 32
#define NEG_SLOPE 0.2f

#define NB 391                   // ceil(N_NODES/256) buckets of 256 dst nodes
#define CHUNK_A 4096
#define BLOCKS_A ((ET + CHUNK_A - 1) / CHUNK_A)
#define BKT_CAP 12288
#define HIST_BLOCKS 400

// v_fma_mix_f32: acc(f32) += f16half(PK) * W(f32); numerically = cvt+fma
#define FMAMIX_LO(ACC, PK, W) \
    asm("v_fma_mix_f32 %0, %1, %2, %0 op_sel:[0,0,0] op_sel_hi:[1,0,0]" \
        : "+v"(ACC) : "v"(PK), "v"(W))
#define FMAMIX_HI(ACC, PK, W) \
    asm("v_fma_mix_f32 %0, %1, %2, %0 op_sel:[1,0,0] op_sel_hi:[1,0,0]" \
        : "+v"(ACC) : "v"(PK), "v"(W))

// ------ bucket histogram: per-block partial counts (no atomics, no memset) ------

__global__ __launch_bounds__(256) void histB_kernel(const int* __restrict__ ei,
                                                    int* __restrict__ bpart) {
    __shared__ int lh[NB];
    for (int i = threadIdx.x; i < NB; i += 256) lh[i] = 0;
    __syncthreads();
    int stride = HIST_BLOCKS * 256;
    for (int e = blockIdx.x * 256 + threadIdx.x; e < N_EDGES; e += stride) {
        int dst = ei[N_EDGES + e];
        atomicAdd(&lh[dst >> 8], 1);
    }
    __syncthreads();
    for (int i = threadIdx.x; i < NB; i += 256)
        bpart[blockIdx.x * NB + i] = lh[i];
}

// ---- bucket scan: sum partials (+self-loops) -> bases/cursors/row_ptr[N] ----

__global__ __launch_bounds__(512) void scanB_kernel(const int* __restrict__ bpart,
                                                    int* __restrict__ bucket_base,
                                                    int* __restrict__ gcursor,
                                                    int* __restrict__ row_ptr) {
    __shared__ int a[NB];
    int t = threadIdx.x;
    int cnt = 0;
    if (t < NB) {
        int v = 0;
        for (int c = 0; c < HIST_BLOCKS; ++c) v += bpart[c * NB + t];
        cnt = v + min(256, N_NODES - (t << 8));   // + self-loops
        a[t] = cnt;
    }
    __syncthreads();
    for (int off = 1; off < NB; off <<= 1) {
        int v = 0;
        if (t < NB && t >= off) v = a[t - off];
        __syncthreads();
        if (t < NB) a[t] += v;
        __syncthreads();
    }
    if (t < NB) {
        int base = a[t] - cnt;
        bucket_base[t] = base;
        gcursor[t] = base;
    }
    if (t == 0) { bucket_base[NB] = ET; row_ptr[N_NODES] = ET; }
}

// ---------------- Pass A: partition edges into 391 dst-buckets ----------------

__global__ __launch_bounds__(256) void partA_kernel(const int* __restrict__ ei,
                                                    int* __restrict__ gcursor,
                                                    unsigned* __restrict__ staging) {
    __shared__ int cnt[NB];
    __shared__ int inc[NB];
    __shared__ int delta[NB];
    __shared__ unsigned stg[CHUNK_A];
    __shared__ unsigned short bkt[CHUNK_A];
    int t = threadIdx.x;
    int begin = blockIdx.x * CHUNK_A;
    int n = min(CHUNK_A, ET - begin);

    for (int i = t; i < NB; i += 256) cnt[i] = 0;
    __syncthreads();

    for (int i = t; i < n; i += 256) {
        int e = begin + i;
        int dst = (e < N_EDGES) ? ei[N_EDGES + e] : (e - N_EDGES);
        atomicAdd(&cnt[dst >> 8], 1);
    }
    __syncthreads();

    for (int i = t; i < NB; i += 256) inc[i] = cnt[i];
    __syncthreads();
    for (int off = 1; off < NB; off <<= 1) {
        int i0 = t, i1 = t + 256;
        int v0 = (i0 < NB && i0 >= off) ? inc[i0 - off] : 0;
        int v1 = (i1 < NB && i1 >= off) ? inc[i1 - off] : 0;
        __syncthreads();
        if (i0 < NB) inc[i0] += v0;
        if (i1 < NB) inc[i1] += v1;
        __syncthreads();
    }

    for (int i = t; i < NB; i += 256) {
        int c = cnt[i];
        int ls = inc[i] - c;
        int g = (c > 0) ? atomicAdd(&gcursor[i], c) : 0;
        delta[i] = g - ls;
        cnt[i] = ls;
    }
    __syncthreads();

    for (int i = t; i < n; i += 256) {
        int e = begin + i;
        int src, dst;
        if (e < N_EDGES) { src = ei[e]; dst = ei[N_EDGES + e]; }
        else             { src = dst = e - N_EDGES; }
        int b = dst >> 8;
        int pos = atomicAdd(&cnt[b], 1);
        stg[pos] = ((unsigned)(dst & 255) << 17) | (unsigned)src;
        bkt[pos] = (unsigned short)b;
    }
    __syncthreads();

    for (int i = t; i < n; i += 256) {
        staging[delta[bkt[i]] + i] = stg[i];
    }
}

// ------- Pass B: per-bucket node-hist + scan (writes row_ptr) + counting sort --

__global__ __launch_bounds__(256) void partB_kernel(const unsigned* __restrict__ staging,
                                                    const int* __restrict__ bucket_base,
                                                    int* __restrict__ row_ptr,
                                                    int* __restrict__ src_sorted) {
    __shared__ int out_s[BKT_CAP];
    __shared__ int a[256];
    __shared__ int cur[256];
    int b = blockIdx.x, t = threadIdx.x;
    int nb0 = b << 8;
    int nn = min(256, N_NODES - nb0);
    int g0 = bucket_base[b];
    int g1 = bucket_base[b + 1];
    int n = g1 - g0;

    cur[t] = 0;
    __syncthreads();
    for (int i = t; i < n; i += 256)
        atomicAdd(&cur[staging[g0 + i] >> 17], 1);
    __syncthreads();

    int v = cur[t];
    a[t] = v;
    __syncthreads();
    for (int off = 1; off < 256; off <<= 1) {
        int w = (t >= off) ? a[t - off] : 0;
        __syncthreads();
        a[t] += w;
        __syncthreads();
    }
    int pref = a[t] - v;
    cur[t] = pref;
    if (t < nn) row_ptr[nb0 + t] = g0 + pref;
    __syncthreads();

    for (int i = t; i < n; i += 256) {
        unsigned u = staging[g0 + i];
        int pos = atomicAdd(&cur[u >> 17], 1);
        out_s[pos] = (int)(u & 0x1FFFFu);
    }
    __syncthreads();
    for (int i = t; i < n; i += 256)
        src_sorted[g0 + i] = out_s[i];
}

// ---------------- Layer 1 GEMM: h1 (fp16) = x @ W1 (+ as1/ad1) ----------

__global__ __launch_bounds__(256) void gemm1_kernel(const float* __restrict__ x,
                                                    const float* __restrict__ W,
                                                    const float* __restrict__ a_src,
                                                    const float* __restrict__ a_dst,
                                                    __half* __restrict__ h,
                                                    float* __restrict__ as,
                                                    float* __restrict__ ad) {
    __shared__ float Wl[IN_F * HID_F];      // 32 KB
    __shared__ float Xl[64 * 132];          // 33.8 KB
    int t = threadIdx.x;
    int base = blockIdx.x * 64;

    for (int i = t; i < IN_F * HID_F / 4; i += 256)
        ((float4*)Wl)[i] = ((const float4*)W)[i];
#pragma unroll
    for (int i = 0; i < 8; ++i) {
        int f4 = t + 256 * i;
        int r = f4 >> 5, c4 = f4 & 31;
        int gr = base + r; if (gr >= N_NODES) gr = N_NODES - 1;
        ((float4*)Xl)[r * 33 + c4] = ((const float4*)(x + (size_t)gr * IN_F))[c4];
    }
    __syncthreads();

    int tx = t & 15, ty = t >> 4;
    int col = tx * 4, row0 = ty * 4;

    float4 acc0 = {0,0,0,0}, acc1 = {0,0,0,0}, acc2 = {0,0,0,0}, acc3 = {0,0,0,0};

#pragma unroll 4
    for (int k = 0; k < IN_F; k += 4) {
        float4 xv0 = *(const float4*)&Xl[(row0 + 0) * 132 + k];
        float4 xv1 = *(const float4*)&Xl[(row0 + 1) * 132 + k];
        float4 xv2 = *(const float4*)&Xl[(row0 + 2) * 132 + k];
        float4 xv3 = *(const float4*)&Xl[(row0 + 3) * 132 + k];
        float4 wv0 = *(const float4*)&Wl[(k + 0) * HID_F + col];
        float4 wv1 = *(const float4*)&Wl[(k + 1) * HID_F + col];
        float4 wv2 = *(const float4*)&Wl[(k + 2) * HID_F + col];
        float4 wv3 = *(const float4*)&Wl[(k + 3) * HID_F + col];
#define G1STEP(A, XV) \
        A.x = fmaf(XV.x, wv0.x, A.x); A.y = fmaf(XV.x, wv0.y, A.y); \
        A.z = fmaf(XV.x, wv0.z, A.z); A.w = fmaf(XV.x, wv0.w, A.w); \
        A.x = fmaf(XV.y, wv1.x, A.x); A.y = fmaf(XV.y, wv1.y, A.y); \
        A.z = fmaf(XV.y, wv1.z, A.z); A.w = fmaf(XV.y, wv1.w, A.w); \
        A.x = fmaf(XV.z, wv2.x, A.x); A.y = fmaf(XV.z, wv2.y, A.y); \
        A.z = fmaf(XV.z, wv2.z, A.z); A.w = fmaf(XV.z, wv2.w, A.w); \
        A.x = fmaf(XV.w, wv3.x, A.x); A.y = fmaf(XV.w, wv3.y, A.y); \
        A.z = fmaf(XV.w, wv3.z, A.z); A.w = fmaf(XV.w, wv3.w, A.w);
        G1STEP(acc0, xv0) G1STEP(acc1, xv1) G1STEP(acc2, xv2) G1STEP(acc3, xv3)
#undef G1STEP
    }

    float4 av = *(const float4*)&a_src[col];
    float4 dv = *(const float4*)&a_dst[col];
#define G1OUT(I, A) { \
        int grow = base + row0 + I; \
        float vs = A.x*av.x + A.y*av.y + A.z*av.z + A.w*av.w; \
        float vd = A.x*dv.x + A.y*dv.y + A.z*dv.z + A.w*dv.w; \
        vs += __shfl_xor(vs, 1, 64); vd += __shfl_xor(vd, 1, 64); \
        vs += __shfl_xor(vs, 2, 64); vd += __shfl_xor(vd, 2, 64); \
        vs += __shfl_xor(vs, 4, 64); vd += __shfl_xor(vd, 4, 64); \
        vs += __shfl_xor(vs, 8, 64); vd += __shfl_xor(vd, 8, 64); \
        if (grow < N_NODES) { \
            __half2 p0 = __floats2half2_rn(A.x, A.y); \
            __half2 p1 = __floats2half2_rn(A.z, A.w); \
            __half2* hp = (__half2*)&h[(size_t)grow * HID_F + col]; \
            hp[0] = p0; hp[1] = p1; \
            if (tx == 0) { as[grow] = vs; ad[grow] = vd; } \
        } }
    G1OUT(0, acc0) G1OUT(1, acc1) G1OUT(2, acc2) G1OUT(3, acc3)
#undef G1OUT
}

// ---- Layer 1 aggregation: no-max softmax, 8-deep fp16 gathers, v_fma_mix ----

__global__ __launch_bounds__(256) void agg1_kernel(const __half* __restrict__ h,
                                                   const float* __restrict__ as,
                                                   const float* __restrict__ ad,
                                                   const int* __restrict__ row_ptr,
                                                   const int* __restrict__ src_sorted,
                                                   const float* __restrict__ b,
                                                   float* __restrict__ r1) {
    int n = blockIdx.x * 4 + (threadIdx.x >> 6);
    int lane = threadIdx.x & 63;
    if (n >= N_NODES) return;
    int beg = row_ptr[n], end = row_ptr[n + 1];
    float adn = ad[n];

    // stage first <=64 edges: sidx + unnormalized weight p per lane
    int e0 = beg + lane;
    int sidx = 0;
    float p = 0.f;
    if (e0 < end) {
        sidx = src_sorted[e0];
        float t = as[sidx] + adn;
        t = (t >= 0.f) ? t : NEG_SLOPE * t;
        p = __expf(t);
    }
    float s = p;

    int g  = lane >> 3;        // 8 groups of 8 lanes; one edge per group per round
    int ho = (lane & 7) * 8;   // 8 halves (16B) per lane covers the 64-feature row

    float4 aL = {0,0,0,0}, aH = {0,0,0,0};
#define ACC1(V, W) { \
        FMAMIX_LO(aL.x, V.x, W); FMAMIX_HI(aL.y, V.x, W); \
        FMAMIX_LO(aL.z, V.y, W); FMAMIX_HI(aL.w, V.y, W); \
        FMAMIX_LO(aH.x, V.z, W); FMAMIX_HI(aH.y, V.z, W); \
        FMAMIX_LO(aH.z, V.w, W); FMAMIX_HI(aH.w, V.w, W); }

    // all 8 rounds issued upfront: 8 loads in flight; padded slots carry p=0
    float ws[8]; int ss[8];
#pragma unroll
    for (int k = 0; k < 8; ++k) {
        ws[k] = __shfl(p,    k * 8 + g, 64);
        ss[k] = __shfl(sidx, k * 8 + g, 64);
    }
    uint4 vv[8];
#pragma unroll
    for (int k = 0; k < 8; ++k)
        vv[k] = *(const uint4*)&h[(unsigned)ss[k] * HID_F + ho];
#pragma unroll
    for (int k = 0; k < 8; ++k) ACC1(vv[k], ws[k])

    // rare deg>64 remainder: stage chunk, accumulate unnormalized, extend s
    for (int cb = beg + 64; cb < end; cb += 64) {
        int e = cb + lane;
        float pr = 0.f;
        int sr = 0;
        if (e < end) {
            sr = src_sorted[e];
            float t = as[sr] + adn;
            t = (t >= 0.f) ? t : NEG_SLOPE * t;
            pr = __expf(t);
            s += pr;
        }
        int cnt = min(64, end - cb);
        int rr = (cnt + 7) >> 3;
        for (int k = 0; k < rr; ++k) {
            float wk = __shfl(pr, k * 8 + g, 64);
            int   sk = __shfl(sr, k * 8 + g, 64);
            uint4 hv = *(const uint4*)&h[(unsigned)sk * HID_F + ho];
            ACC1(hv, wk)
        }
    }
#undef ACC1

    // butterfly sum of s over all 64 lanes
    s += __shfl_xor(s, 32, 64); s += __shfl_xor(s, 16, 64); s += __shfl_xor(s, 8, 64);
    s += __shfl_xor(s, 4, 64);  s += __shfl_xor(s, 2, 64);  s += __shfl_xor(s, 1, 64);
    float invs = __builtin_amdgcn_rcpf(s);

#define RED1(C) C += __shfl_xor(C, 8, 64); C += __shfl_xor(C, 16, 64); C += __shfl_xor(C, 32, 64);
    RED1(aL.x) RED1(aL.y) RED1(aL.z) RED1(aL.w)
    RED1(aH.x) RED1(aH.y) RED1(aH.z) RED1(aH.w)
#undef RED1

    if (lane < 8) {
        int fo = lane * 8;
        float4 b0 = *(const float4*)&b[fo];
        float4 b1 = *(const float4*)&b[fo + 4];
        float4 vL, vH;
        vL.x = fmaxf(fmaf(aL.x, invs, b0.x), 0.f); vL.y = fmaxf(fmaf(aL.y, invs, b0.y), 0.f);
        vL.z = fmaxf(fmaf(aL.z, invs, b0.z), 0.f); vL.w = fmaxf(fmaf(aL.w, invs, b0.w), 0.f);
        vH.x = fmaxf(fmaf(aH.x, invs, b1.x), 0.f); vH.y = fmaxf(fmaf(aH.y, invs, b1.y), 0.f);
        vH.z = fmaxf(fmaf(aH.z, invs, b1.z), 0.f); vH.w = fmaxf(fmaf(aH.w, invs, b1.w), 0.f);
        *(float4*)&r1[(size_t)n * HID_F + fo] = vL;
        *(float4*)&r1[(size_t)n * HID_F + fo + 4] = vH;
    }
}

// ------- Layer 2 GEMM: h2 (fp16) = r1 @ W2 (+ as2/ad2), LDS-tiled 4x4 ---------

__global__ __launch_bounds__(256) void gemm2_kernel(const float* __restrict__ r1,
                                                    const float* __restrict__ W,
                                                    const float* __restrict__ a_src,
                                                    const float* __restrict__ a_dst,
                                                    __half* __restrict__ h2,
                                                    float* __restrict__ as2,
                                                    float* __restrict__ ad2) {
    __shared__ float Wl[HID_F * OUT_F];     // 8 KB
    __shared__ float Xl[128 * 68];          // 34.8 KB
    int t = threadIdx.x;
    int base = blockIdx.x * 128;

    for (int i = t; i < HID_F * OUT_F / 4; i += 256)
        ((float4*)Wl)[i] = ((const float4*)W)[i];
#pragma unroll
    for (int i = 0; i < 8; ++i) {
        int f4 = t + 256 * i;
        int r = f4 >> 4, c4 = f4 & 15;
        int gr = base + r; if (gr >= N_NODES) gr = N_NODES - 1;
        ((float4*)Xl)[r * 17 + c4] = ((const float4*)(r1 + (size_t)gr * HID_F))[c4];
    }
    __syncthreads();

    int tx = t & 7, ty = t >> 3;
    int col = tx * 4, row0 = ty * 4;

    float4 acc0 = {0,0,0,0}, acc1 = {0,0,0,0}, acc2 = {0,0,0,0}, acc3 = {0,0,0,0};

#pragma unroll 4
    for (int k = 0; k < HID_F; k += 4) {
        float4 xv0 = *(const float4*)&Xl[(row0 + 0) * 68 + k];
        float4 xv1 = *(const float4*)&Xl[(row0 + 1) * 68 + k];
        float4 xv2 = *(const float4*)&Xl[(row0 + 2) * 68 + k];
        float4 xv3 = *(const float4*)&Xl[(row0 + 3) * 68 + k];
        float4 wv0 = *(const float4*)&Wl[(k + 0) * OUT_F + col];
        float4 wv1 = *(const float4*)&Wl[(k + 1) * OUT_F + col];
        float4 wv2 = *(const float4*)&Wl[(k + 2) * OUT_F + col];
        float4 wv3 = *(const float4*)&Wl[(k + 3) * OUT_F + col];
#define G2STEP(A, XV) \
        A.x = fmaf(XV.x, wv0.x, A.x); A.y = fmaf(XV.x, wv0.y, A.y); \
        A.z = fmaf(XV.x, wv0.z, A.z); A.w = fmaf(XV.x, wv0.w, A.w); \
        A.x = fmaf(XV.y, wv1.x, A.x); A.y = fmaf(XV.y, wv1.y, A.y); \
        A.z = fmaf(XV.y, wv1.z, A.z); A.w = fmaf(XV.y, wv1.w, A.w); \
        A.x = fmaf(XV.z, wv2.x, A.x); A.y = fmaf(XV.z, wv2.y, A.y); \
        A.z = fmaf(XV.z, wv2.z, A.z); A.w = fmaf(XV.z, wv2.w, A.w); \
        A.x = fmaf(XV.w, wv3.x, A.x); A.y = fmaf(XV.w, wv3.y, A.y); \
        A.z = fmaf(XV.w, wv3.z, A.z); A.w = fmaf(XV.w, wv3.w, A.w);
        G2STEP(acc0, xv0) G2STEP(acc1, xv1) G2STEP(acc2, xv2) G2STEP(acc3, xv3)
#undef G2STEP
    }

    float4 av = *(const float4*)&a_src[col];
    float4 dv = *(const float4*)&a_dst[col];
#define G2OUT(I, A) { \
        int grow = base + row0 + I; \
        float vs = A.x*av.x + A.y*av.y + A.z*av.z + A.w*av.w; \
        float vd = A.x*dv.x + A.y*dv.y + A.z*dv.z + A.w*dv.w; \
        vs += __shfl_xor(vs, 1, 64); vd += __shfl_xor(vd, 1, 64); \
        vs += __shfl_xor(vs, 2, 64); vd += __shfl_xor(vd, 2, 64); \
        vs += __shfl_xor(vs, 4, 64); vd += __shfl_xor(vd, 4, 64); \
        if (grow < N_NODES) { \
            __half2 p0 = __floats2half2_rn(A.x, A.y); \
            __half2 p1 = __floats2half2_rn(A.z, A.w); \
            __half2* hp = (__half2*)&h2[(size_t)grow * OUT_F + col]; \
            hp[0] = p0; hp[1] = p1; \
            if (tx == 0) { as2[grow] = vs; ad2[grow] = vd; } \
        } }
    G2OUT(0, acc0) G2OUT(1, acc1) G2OUT(2, acc2) G2OUT(3, acc3)
#undef G2OUT
}

// ---- Layer 2 aggregation: no-max softmax, 8-deep fp16 gathers, v_fma_mix ----

__global__ __launch_bounds__(256) void agg2_kernel(const __half* __restrict__ h2,
                                                   const float* __restrict__ as2,
                                                   const float* __restrict__ ad2,
                                                   const int* __restrict__ row_ptr,
                                                   const int* __restrict__ src_sorted,
                                                   const float* __restrict__ b2,
                                                   float* __restrict__ out) {
    int n = blockIdx.x * 4 + (threadIdx.x >> 6);
    int lane = threadIdx.x & 63;
    if (n >= N_NODES) return;
    int beg = row_ptr[n], end = row_ptr[n + 1];
    float adn = ad2[n];

    int e0 = beg + lane;
    int sidx = 0;
    float p = 0.f;
    if (e0 < end) {
        sidx = src_sorted[e0];
        float t = as2[sidx] + adn;
        t = (t >= 0.f) ? t : NEG_SLOPE * t;
        p = __expf(t);
    }
    float s = p;

    int g  = lane >> 3;       // 8 groups of 8 lanes; one edge per group per round
    int ho = (lane & 7) * 4;  // 4 halves (8B) per lane covers the 32-feature row

    float4 acc = {0.f, 0.f, 0.f, 0.f};
#define ACC2(V, W) { \
        FMAMIX_LO(acc.x, V.x, W); FMAMIX_HI(acc.y, V.x, W); \
        FMAMIX_LO(acc.z, V.y, W); FMAMIX_HI(acc.w, V.y, W); }

    float ws[8]; int ss[8];
#pragma unroll
    for (int k = 0; k < 8; ++k) {
        ws[k] = __shfl(p,    k * 8 + g, 64);
        ss[k] = __shfl(sidx, k * 8 + g, 64);
    }
    uint2 q[8];
#pragma unroll
    for (int k = 0; k < 8; ++k)
        q[k] = *(const uint2*)&h2[(unsigned)ss[k] * OUT_F + ho];
#pragma unroll
    for (int k = 0; k < 8; ++k) ACC2(q[k], ws[k])

    for (int cb = beg + 64; cb < end; cb += 64) {   // rare deg>64 remainder
        int e = cb + lane;
        float pr = 0.f;
        int sr = 0;
        if (e < end) {
            sr = src_sorted[e];
            float t = as2[sr] + adn;
            t = (t >= 0.f) ? t : NEG_SLOPE * t;
            pr = __expf(t);
            s += pr;
        }
        int cnt = min(64, end - cb);
        int rr = (cnt + 7) >> 3;
        for (int k = 0; k < rr; ++k) {
            float wk = __shfl(pr, k * 8 + g, 64);
            int   sk = __shfl(sr, k * 8 + g, 64);
            uint2 hv = *(const uint2*)&h2[(unsigned)sk * OUT_F + ho];
            ACC2(hv, wk)
        }
    }
#undef ACC2

    s += __shfl_xor(s, 32, 64); s += __shfl_xor(s, 16, 64); s += __shfl_xor(s, 8, 64);
    s += __shfl_xor(s, 4, 64);  s += __shfl_xor(s, 2, 64);  s += __shfl_xor(s, 1, 64);
    float invs = __builtin_amdgcn_rcpf(s);

    acc.x += __shfl_xor(acc.x, 8, 64); acc.x += __shfl_xor(acc.x, 16, 64); acc.x += __shfl_xor(acc.x, 32, 64);
    acc.y += __shfl_xor(acc.y, 8, 64); acc.y += __shfl_xor(acc.y, 16, 64); acc.y += __shfl_xor(acc.y, 32, 64);
    acc.z += __shfl_xor(acc.z, 8, 64); acc.z += __shfl_xor(acc.z, 16, 64); acc.z += __shfl_xor(acc.z, 32, 64);
    acc.w += __shfl_xor(acc.w, 8, 64); acc.w += __shfl_xor(acc.w, 16, 64); acc.w += __shfl_xor(acc.w, 32, 64);

    int fo = (lane & 7) * 4;
    float4 bv = *(const float4*)&b2[fo];
    float4 v;
    v.x = fmaf(acc.x, invs, bv.x); v.y = fmaf(acc.y, invs, bv.y);
    v.z = fmaf(acc.z, invs, bv.z); v.w = fmaf(acc.w, invs, bv.w);

    // row softmax over 32 features; |v| <= ~10 -> no max subtraction needed
    float4 ev;
    ev.x = __expf(v.x); ev.y = __expf(v.y);
    ev.z = __expf(v.z); ev.w = __expf(v.w);
    float ls = ev.x + ev.y + ev.z + ev.w;
    ls += __shfl_xor(ls, 1, 64);
    ls += __shfl_xor(ls, 2, 64);
    ls += __shfl_xor(ls, 4, 64);
    float invl = __builtin_amdgcn_rcpf(ls);
    if (lane < 8) {
        float4 o;
        o.x = ev.x * invl; o.y = ev.y * invl; o.z = ev.z * invl; o.w = ev.w * invl;
        *(float4*)&out[(size_t)n * OUT_F + fo] = o;
    }
}

// ---------------- launch ----------------

extern "C" void kernel_launch(void* const* d_in, const int* in_sizes, int n_in,
                              void* d_out, int out_size, void* d_ws, size_t ws_size,
                              hipStream_t stream) {
    const float* x     = (const float*)d_in[0];
    const int*   ei    = (const int*)d_in[1];
    const float* W1    = (const float*)d_in[2];
    const float* asrc1 = (const float*)d_in[3];
    const float* adst1 = (const float*)d_in[4];
    const float* b1    = (const float*)d_in[5];
    const float* W2    = (const float*)d_in[6];
    const float* asrc2 = (const float*)d_in[7];
    const float* adst2 = (const float*)d_in[8];
    const float* b2    = (const float*)d_in[9];
    float* out = (float*)d_out;

    char* p = (char*)d_ws;
    auto alloc = [&](size_t bytes) {
        char* q = p;
        p += (bytes + 255) & ~size_t(255);
        return q;
    };
    int*    row_ptr     = (int*)   alloc(sizeof(int) * (N_NODES + 1));
    int*    bpart       = (int*)   alloc(sizeof(int) * (size_t)HIST_BLOCKS * NB);
    int*    bucket_base = (int*)   alloc(sizeof(int) * (NB + 1));
    int*    gcursor     = (int*)   alloc(sizeof(int) * NB);
    int*    src_sorted  = (int*)   alloc(sizeof(int) * (size_t)ET);
    __half* h1          = (__half*)alloc(sizeof(__half) * (size_t)N_NODES * HID_F);
    float*  as1         = (float*) alloc(sizeof(float) * N_NODES);
    float*  ad1         = (float*) alloc(sizeof(float) * N_NODES);
    float*  r1          = (float*) alloc(sizeof(float) * (size_t)N_NODES * HID_F);
    __half* h2          = (__half*)alloc(sizeof(__half) * (size_t)N_NODES * OUT_F);
    float*  as2v        = (float*) alloc(sizeof(float) * N_NODES);
    float*  ad2v        = (float*) alloc(sizeof(float) * N_NODES);
    unsigned* staging   = (unsigned*)r1;   // aliases r1; dead before agg1 writes r1

    hipLaunchKernelGGL(histB_kernel, dim3(HIST_BLOCKS), dim3(256), 0, stream, ei, bpart);
    hipLaunchKernelGGL(scanB_kernel, dim3(1), dim3(512), 0, stream,
                       bpart, bucket_base, gcursor, row_ptr);
    hipLaunchKernelGGL(partA_kernel, dim3(BLOCKS_A), dim3(256), 0, stream, ei, gcursor, staging);
    hipLaunchKernelGGL(partB_kernel, dim3(NB), dim3(256), 0, stream,
                       staging, bucket_base, row_ptr, src_sorted);
    hipLaunchKernelGGL(gemm1_kernel, dim3((N_NODES + 63) / 64), dim3(256), 0, stream,
                       x, W1, asrc1, adst1, h1, as1, ad1);
    hipLaunchKernelGGL(agg1_kernel, dim3((N_NODES + 3) / 4), dim3(256), 0, stream,
                       h1, as1, ad1, row_ptr, src_sorted, b1, r1);
    hipLaunchKernelGGL(gemm2_kernel, dim3((N_NODES + 127) / 128), dim3(256), 0, stream,
                       r1, W2, asrc2, adst2, h2, as2v, ad2v);
    hipLaunchKernelGGL(agg2_kernel, dim3((N_NODES + 3) / 4), dim3(256), 0, stream,
                       h2, as2v, ad2v, row_ptr, src_sorted, b2, out);
}

// Round 11
// 235.744 us; speedup vs baseline: 1.0212x; 1.0212x over previous
//
#include <hip/hip_runtime.h>
#include <hip/hip_fp16.h>

#define N_NODES 100000
#define N_EDGES 3200000
#define ET (N_EDGES + N_NODES)   // edges + self-loops
#define IN_F 128
#define HID_F 64
#define OUT_F 32
#define NEG_SLOPE 0.2f

#define NB 391                   // ceil(N_NODES/256) buckets of 256 dst nodes
#define CHUNK_A 8192
#define BLOCKS_A ((ET + CHUNK_A - 1) / CHUNK_A)
#define BKT_CAP 12288
#define HIST_BLOCKS 400

// v_fma_mix_f32: acc(f32) += f16half(PK) * W(f32); numerically = cvt+fma
#define FMAMIX_LO(ACC, PK, W) \
    asm("v_fma_mix_f32 %0, %1, %2, %0 op_sel:[0,0,0] op_sel_hi:[1,0,0]" \
        : "+v"(ACC) : "v"(PK), "v"(W))
#define FMAMIX_HI(ACC, PK, W) \
    asm("v_fma_mix_f32 %0, %1, %2, %0 op_sel:[1,0,0] op_sel_hi:[1,0,0]" \
        : "+v"(ACC) : "v"(PK), "v"(W))

// ------ bucket histogram: per-block partial counts (no atomics, no memset) ------

__global__ __launch_bounds__(256) void histB_kernel(const int* __restrict__ ei,
                                                    int* __restrict__ bpart) {
    __shared__ int lh[NB];
    for (int i = threadIdx.x; i < NB; i += 256) lh[i] = 0;
    __syncthreads();
    int stride = HIST_BLOCKS * 256;
    for (int e = blockIdx.x * 256 + threadIdx.x; e < N_EDGES; e += stride) {
        int dst = ei[N_EDGES + e];
        atomicAdd(&lh[dst >> 8], 1);
    }
    __syncthreads();
    for (int i = threadIdx.x; i < NB; i += 256)
        bpart[blockIdx.x * NB + i] = lh[i];
}

// ---- bucket scan: sum partials (+self-loops) -> bases/cursors/row_ptr[N] ----

__global__ __launch_bounds__(512) void scanB_kernel(const int* __restrict__ bpart,
                                                    int* __restrict__ bucket_base,
                                                    int* __restrict__ gcursor,
                                                    int* __restrict__ row_ptr) {
    __shared__ int a[NB];
    int t = threadIdx.x;
    int cnt = 0;
    if (t < NB) {
        int v = 0;
        for (int c = 0; c < HIST_BLOCKS; ++c) v += bpart[c * NB + t];
        cnt = v + min(256, N_NODES - (t << 8));   // + self-loops
        a[t] = cnt;
    }
    __syncthreads();
    for (int off = 1; off < NB; off <<= 1) {
        int v = 0;
        if (t < NB && t >= off) v = a[t - off];
        __syncthreads();
        if (t < NB) a[t] += v;
        __syncthreads();
    }
    if (t < NB) {
        int base = a[t] - cnt;
        bucket_base[t] = base;
        gcursor[t] = base;
    }
    if (t == 0) { bucket_base[NB] = ET; row_ptr[N_NODES] = ET; }
}

// ---------------- Pass A: partition edges into 391 dst-buckets ----------------

__global__ __launch_bounds__(256) void partA_kernel(const int* __restrict__ ei,
                                                    int* __restrict__ gcursor,
                                                    unsigned* __restrict__ staging) {
    __shared__ int cnt[NB];
    __shared__ int inc[NB];
    __shared__ int delta[NB];
    __shared__ unsigned stg[CHUNK_A];
    __shared__ unsigned short bkt[CHUNK_A];
    int t = threadIdx.x;
    int begin = blockIdx.x * CHUNK_A;
    int n = min(CHUNK_A, ET - begin);

    for (int i = t; i < NB; i += 256) cnt[i] = 0;
    __syncthreads();

    for (int i = t; i < n; i += 256) {
        int e = begin + i;
        int dst = (e < N_EDGES) ? ei[N_EDGES + e] : (e - N_EDGES);
        atomicAdd(&cnt[dst >> 8], 1);
    }
    __syncthreads();

    for (int i = t; i < NB; i += 256) inc[i] = cnt[i];
    __syncthreads();
    for (int off = 1; off < NB; off <<= 1) {
        int i0 = t, i1 = t + 256;
        int v0 = (i0 < NB && i0 >= off) ? inc[i0 - off] : 0;
        int v1 = (i1 < NB && i1 >= off) ? inc[i1 - off] : 0;
        __syncthreads();
        if (i0 < NB) inc[i0] += v0;
        if (i1 < NB) inc[i1] += v1;
        __syncthreads();
    }

    for (int i = t; i < NB; i += 256) {
        int c = cnt[i];
        int ls = inc[i] - c;
        int g = (c > 0) ? atomicAdd(&gcursor[i], c) : 0;
        delta[i] = g - ls;
        cnt[i] = ls;
    }
    __syncthreads();

    for (int i = t; i < n; i += 256) {
        int e = begin + i;
        int src, dst;
        if (e < N_EDGES) { src = ei[e]; dst = ei[N_EDGES + e]; }
        else             { src = dst = e - N_EDGES; }
        int b = dst >> 8;
        int pos = atomicAdd(&cnt[b], 1);
        stg[pos] = ((unsigned)(dst & 255) << 17) | (unsigned)src;
        bkt[pos] = (unsigned short)b;
    }
    __syncthreads();

    for (int i = t; i < n; i += 256) {
        staging[delta[bkt[i]] + i] = stg[i];
    }
}

// ------- Pass B: per-bucket node-hist + scan (writes row_ptr) + counting sort --

__global__ __launch_bounds__(256) void partB_kernel(const unsigned* __restrict__ staging,
                                                    const int* __restrict__ bucket_base,
                                                    int* __restrict__ row_ptr,
                                                    int* __restrict__ src_sorted) {
    __shared__ int out_s[BKT_CAP];
    __shared__ int a[256];
    __shared__ int cur[256];
    int b = blockIdx.x, t = threadIdx.x;
    int nb0 = b << 8;
    int nn = min(256, N_NODES - nb0);
    int g0 = bucket_base[b];
    int g1 = bucket_base[b + 1];
    int n = g1 - g0;

    cur[t] = 0;
    __syncthreads();
    for (int i = t; i < n; i += 256)
        atomicAdd(&cur[staging[g0 + i] >> 17], 1);
    __syncthreads();

    int v = cur[t];
    a[t] = v;
    __syncthreads();
    for (int off = 1; off < 256; off <<= 1) {
        int w = (t >= off) ? a[t - off] : 0;
        __syncthreads();
        a[t] += w;
        __syncthreads();
    }
    int pref = a[t] - v;
    cur[t] = pref;
    if (t < nn) row_ptr[nb0 + t] = g0 + pref;
    __syncthreads();

    for (int i = t; i < n; i += 256) {
        unsigned u = staging[g0 + i];
        int pos = atomicAdd(&cur[u >> 17], 1);
        out_s[pos] = (int)(u & 0x1FFFFu);
    }
    __syncthreads();
    for (int i = t; i < n; i += 256)
        src_sorted[g0 + i] = out_s[i];
}

// ---------------- Layer 1 GEMM: h1 (fp16) = x @ W1 (+ as1/ad1) ----------

__global__ __launch_bounds__(256) void gemm1_kernel(const float* __restrict__ x,
                                                    const float* __restrict__ W,
                                                    const float* __restrict__ a_src,
                                                    const float* __restrict__ a_dst,
                                                    __half* __restrict__ h,
                                                    float* __restrict__ as,
                                                    float* __restrict__ ad) {
    __shared__ float Wl[IN_F * HID_F];      // 32 KB
    __shared__ float Xl[64 * 132];          // 33.8 KB
    int t = threadIdx.x;
    int base = blockIdx.x * 64;

    for (int i = t; i < IN_F * HID_F / 4; i += 256)
        ((float4*)Wl)[i] = ((const float4*)W)[i];
#pragma unroll
    for (int i = 0; i < 8; ++i) {
        int f4 = t + 256 * i;
        int r = f4 >> 5, c4 = f4 & 31;
        int gr = base + r; if (gr >= N_NODES) gr = N_NODES - 1;
        ((float4*)Xl)[r * 33 + c4] = ((const float4*)(x + (size_t)gr * IN_F))[c4];
    }
    __syncthreads();

    int tx = t & 15, ty = t >> 4;
    int col = tx * 4, row0 = ty * 4;

    float4 acc0 = {0,0,0,0}, acc1 = {0,0,0,0}, acc2 = {0,0,0,0}, acc3 = {0,0,0,0};

#pragma unroll 4
    for (int k = 0; k < IN_F; k += 4) {
        float4 xv0 = *(const float4*)&Xl[(row0 + 0) * 132 + k];
        float4 xv1 = *(const float4*)&Xl[(row0 + 1) * 132 + k];
        float4 xv2 = *(const float4*)&Xl[(row0 + 2) * 132 + k];
        float4 xv3 = *(const float4*)&Xl[(row0 + 3) * 132 + k];
        float4 wv0 = *(const float4*)&Wl[(k + 0) * HID_F + col];
        float4 wv1 = *(const float4*)&Wl[(k + 1) * HID_F + col];
        float4 wv2 = *(const float4*)&Wl[(k + 2) * HID_F + col];
        float4 wv3 = *(const float4*)&Wl[(k + 3) * HID_F + col];
#define G1STEP(A, XV) \
        A.x = fmaf(XV.x, wv0.x, A.x); A.y = fmaf(XV.x, wv0.y, A.y); \
        A.z = fmaf(XV.x, wv0.z, A.z); A.w = fmaf(XV.x, wv0.w, A.w); \
        A.x = fmaf(XV.y, wv1.x, A.x); A.y = fmaf(XV.y, wv1.y, A.y); \
        A.z = fmaf(XV.y, wv1.z, A.z); A.w = fmaf(XV.y, wv1.w, A.w); \
        A.x = fmaf(XV.z, wv2.x, A.x); A.y = fmaf(XV.z, wv2.y, A.y); \
        A.z = fmaf(XV.z, wv2.z, A.z); A.w = fmaf(XV.z, wv2.w, A.w); \
        A.x = fmaf(XV.w, wv3.x, A.x); A.y = fmaf(XV.w, wv3.y, A.y); \
        A.z = fmaf(XV.w, wv3.z, A.z); A.w = fmaf(XV.w, wv3.w, A.w);
        G1STEP(acc0, xv0) G1STEP(acc1, xv1) G1STEP(acc2, xv2) G1STEP(acc3, xv3)
#undef G1STEP
    }

    float4 av = *(const float4*)&a_src[col];
    float4 dv = *(const float4*)&a_dst[col];
#define G1OUT(I, A) { \
        int grow = base + row0 + I; \
        float vs = A.x*av.x + A.y*av.y + A.z*av.z + A.w*av.w; \
        float vd = A.x*dv.x + A.y*dv.y + A.z*dv.z + A.w*dv.w; \
        vs += __shfl_xor(vs, 1, 64); vd += __shfl_xor(vd, 1, 64); \
        vs += __shfl_xor(vs, 2, 64); vd += __shfl_xor(vd, 2, 64); \
        vs += __shfl_xor(vs, 4, 64); vd += __shfl_xor(vd, 4, 64); \
        vs += __shfl_xor(vs, 8, 64); vd += __shfl_xor(vd, 8, 64); \
        if (grow < N_NODES) { \
            __half2 p0 = __floats2half2_rn(A.x, A.y); \
            __half2 p1 = __floats2half2_rn(A.z, A.w); \
            __half2* hp = (__half2*)&h[(size_t)grow * HID_F + col]; \
            hp[0] = p0; hp[1] = p1; \
            if (tx == 0) { as[grow] = vs; ad[grow] = vd; } \
        } }
    G1OUT(0, acc0) G1OUT(1, acc1) G1OUT(2, acc2) G1OUT(3, acc3)
#undef G1OUT
}

// ---- Layer 1 aggregation: no-max softmax, 4+4 two-batch fp16 gathers, fma_mix --

__global__ __launch_bounds__(256) void agg1_kernel(const __half* __restrict__ h,
                                                   const float* __restrict__ as,
                                                   const float* __restrict__ ad,
                                                   const int* __restrict__ row_ptr,
                                                   const int* __restrict__ src_sorted,
                                                   const float* __restrict__ b,
                                                   float* __restrict__ r1) {
    int n = blockIdx.x * 4 + (threadIdx.x >> 6);
    int lane = threadIdx.x & 63;
    if (n >= N_NODES) return;
    int beg = row_ptr[n], end = row_ptr[n + 1];
    int deg = end - beg;
    float adn = ad[n];

    // stage first <=64 edges: sidx + unnormalized weight p per lane
    int e0 = beg + lane;
    int sidx = 0;
    float p = 0.f;
    if (e0 < end) {
        sidx = src_sorted[e0];
        float t = as[sidx] + adn;
        t = (t >= 0.f) ? t : NEG_SLOPE * t;
        p = __expf(t);
    }
    float s = p;

    int g  = lane >> 3;        // 8 groups of 8 lanes; one edge per group per round
    int ho = (lane & 7) * 8;   // 8 halves (16B) per lane covers the 64-feature row

    float4 aL = {0,0,0,0}, aH = {0,0,0,0};
#define ACC1(V, W) { \
        FMAMIX_LO(aL.x, V.x, W); FMAMIX_HI(aL.y, V.x, W); \
        FMAMIX_LO(aL.z, V.y, W); FMAMIX_HI(aL.w, V.y, W); \
        FMAMIX_LO(aH.x, V.z, W); FMAMIX_HI(aH.y, V.z, W); \
        FMAMIX_LO(aH.z, V.w, W); FMAMIX_HI(aH.w, V.w, W); }

#define BATCH1(K0) { \
        float ws0 = __shfl(p, (K0 + 0) * 8 + g, 64); \
        float ws1 = __shfl(p, (K0 + 1) * 8 + g, 64); \
        float ws2 = __shfl(p, (K0 + 2) * 8 + g, 64); \
        float ws3 = __shfl(p, (K0 + 3) * 8 + g, 64); \
        int   ss0 = __shfl(sidx, (K0 + 0) * 8 + g, 64); \
        int   ss1 = __shfl(sidx, (K0 + 1) * 8 + g, 64); \
        int   ss2 = __shfl(sidx, (K0 + 2) * 8 + g, 64); \
        int   ss3 = __shfl(sidx, (K0 + 3) * 8 + g, 64); \
        uint4 v0 = *(const uint4*)&h[(unsigned)ss0 * HID_F + ho]; \
        uint4 v1 = *(const uint4*)&h[(unsigned)ss1 * HID_F + ho]; \
        uint4 v2 = *(const uint4*)&h[(unsigned)ss2 * HID_F + ho]; \
        uint4 v3 = *(const uint4*)&h[(unsigned)ss3 * HID_F + ho]; \
        ACC1(v0, ws0) ACC1(v1, ws1) ACC1(v2, ws2) ACC1(v3, ws3) }

    BATCH1(0)                       // edges 0..31 (always)
    if (deg > 32) BATCH1(4)         // edges 32..63 (~48% of nodes)
#undef BATCH1

    // rare deg>64 remainder: stage chunk, accumulate unnormalized, extend s
    for (int cb = beg + 64; cb < end; cb += 64) {
        int e = cb + lane;
        float pr = 0.f;
        int sr = 0;
        if (e < end) {
            sr = src_sorted[e];
            float t = as[sr] + adn;
            t = (t >= 0.f) ? t : NEG_SLOPE * t;
            pr = __expf(t);
            s += pr;
        }
        int cnt = min(64, end - cb);
        int rr = (cnt + 7) >> 3;
        for (int k = 0; k < rr; ++k) {
            float wk = __shfl(pr, k * 8 + g, 64);
            int   sk = __shfl(sr, k * 8 + g, 64);
            uint4 hv = *(const uint4*)&h[(unsigned)sk * HID_F + ho];
            ACC1(hv, wk)
        }
    }
#undef ACC1

    // butterfly sum of s over all 64 lanes
    s += __shfl_xor(s, 32, 64); s += __shfl_xor(s, 16, 64); s += __shfl_xor(s, 8, 64);
    s += __shfl_xor(s, 4, 64);  s += __shfl_xor(s, 2, 64);  s += __shfl_xor(s, 1, 64);
    float invs = __builtin_amdgcn_rcpf(s);

#define RED1(C) C += __shfl_xor(C, 8, 64); C += __shfl_xor(C, 16, 64); C += __shfl_xor(C, 32, 64);
    RED1(aL.x) RED1(aL.y) RED1(aL.z) RED1(aL.w)
    RED1(aH.x) RED1(aH.y) RED1(aH.z) RED1(aH.w)
#undef RED1

    if (lane < 8) {
        int fo = lane * 8;
        float4 b0 = *(const float4*)&b[fo];
        float4 b1 = *(const float4*)&b[fo + 4];
        float4 vL, vH;
        vL.x = fmaxf(fmaf(aL.x, invs, b0.x), 0.f); vL.y = fmaxf(fmaf(aL.y, invs, b0.y), 0.f);
        vL.z = fmaxf(fmaf(aL.z, invs, b0.z), 0.f); vL.w = fmaxf(fmaf(aL.w, invs, b0.w), 0.f);
        vH.x = fmaxf(fmaf(aH.x, invs, b1.x), 0.f); vH.y = fmaxf(fmaf(aH.y, invs, b1.y), 0.f);
        vH.z = fmaxf(fmaf(aH.z, invs, b1.z), 0.f); vH.w = fmaxf(fmaf(aH.w, invs, b1.w), 0.f);
        *(float4*)&r1[(size_t)n * HID_F + fo] = vL;
        *(float4*)&r1[(size_t)n * HID_F + fo + 4] = vH;
    }
}

// ------- Layer 2 GEMM: h2 (fp16) = r1 @ W2 (+ as2/ad2), LDS-tiled 4x4 ---------

__global__ __launch_bounds__(256) void gemm2_kernel(const float* __restrict__ r1,
                                                    const float* __restrict__ W,
                                                    const float* __restrict__ a_src,
                                                    const float* __restrict__ a_dst,
                                                    __half* __restrict__ h2,
                                                    float* __restrict__ as2,
                                                    float* __restrict__ ad2) {
    __shared__ float Wl[HID_F * OUT_F];     // 8 KB
    __shared__ float Xl[128 * 68];          // 34.8 KB
    int t = threadIdx.x;
    int base = blockIdx.x * 128;

    for (int i = t; i < HID_F * OUT_F / 4; i += 256)
        ((float4*)Wl)[i] = ((const float4*)W)[i];
#pragma unroll
    for (int i = 0; i < 8; ++i) {
        int f4 = t + 256 * i;
        int r = f4 >> 4, c4 = f4 & 15;
        int gr = base + r; if (gr >= N_NODES) gr = N_NODES - 1;
        ((float4*)Xl)[r * 17 + c4] = ((const float4*)(r1 + (size_t)gr * HID_F))[c4];
    }
    __syncthreads();

    int tx = t & 7, ty = t >> 3;
    int col = tx * 4, row0 = ty * 4;

    float4 acc0 = {0,0,0,0}, acc1 = {0,0,0,0}, acc2 = {0,0,0,0}, acc3 = {0,0,0,0};

#pragma unroll 4
    for (int k = 0; k < HID_F; k += 4) {
        float4 xv0 = *(const float4*)&Xl[(row0 + 0) * 68 + k];
        float4 xv1 = *(const float4*)&Xl[(row0 + 1) * 68 + k];
        float4 xv2 = *(const float4*)&Xl[(row0 + 2) * 68 + k];
        float4 xv3 = *(const float4*)&Xl[(row0 + 3) * 68 + k];
        float4 wv0 = *(const float4*)&Wl[(k + 0) * OUT_F + col];
        float4 wv1 = *(const float4*)&Wl[(k + 1) * OUT_F + col];
        float4 wv2 = *(const float4*)&Wl[(k + 2) * OUT_F + col];
        float4 wv3 = *(const float4*)&Wl[(k + 3) * OUT_F + col];
#define G2STEP(A, XV) \
        A.x = fmaf(XV.x, wv0.x, A.x); A.y = fmaf(XV.x, wv0.y, A.y); \
        A.z = fmaf(XV.x, wv0.z, A.z); A.w = fmaf(XV.x, wv0.w, A.w); \
        A.x = fmaf(XV.y, wv1.x, A.x); A.y = fmaf(XV.y, wv1.y, A.y); \
        A.z = fmaf(XV.y, wv1.z, A.z); A.w = fmaf(XV.y, wv1.w, A.w); \
        A.x = fmaf(XV.z, wv2.x, A.x); A.y = fmaf(XV.z, wv2.y, A.y); \
        A.z = fmaf(XV.z, wv2.z, A.z); A.w = fmaf(XV.z, wv2.w, A.w); \
        A.x = fmaf(XV.w, wv3.x, A.x); A.y = fmaf(XV.w, wv3.y, A.y); \
        A.z = fmaf(XV.w, wv3.z, A.z); A.w = fmaf(XV.w, wv3.w, A.w);
        G2STEP(acc0, xv0) G2STEP(acc1, xv1) G2STEP(acc2, xv2) G2STEP(acc3, xv3)
#undef G2STEP
    }

    float4 av = *(const float4*)&a_src[col];
    float4 dv = *(const float4*)&a_dst[col];
#define G2OUT(I, A) { \
        int grow = base + row0 + I; \
        float vs = A.x*av.x + A.y*av.y + A.z*av.z + A.w*av.w; \
        float vd = A.x*dv.x + A.y*dv.y + A.z*dv.z + A.w*dv.w; \
        vs += __shfl_xor(vs, 1, 64); vd += __shfl_xor(vd, 1, 64); \
        vs += __shfl_xor(vs, 2, 64); vd += __shfl_xor(vd, 2, 64); \
        vs += __shfl_xor(vs, 4, 64); vd += __shfl_xor(vd, 4, 64); \
        if (grow < N_NODES) { \
            __half2 p0 = __floats2half2_rn(A.x, A.y); \
            __half2 p1 = __floats2half2_rn(A.z, A.w); \
            __half2* hp = (__half2*)&h2[(size_t)grow * OUT_F + col]; \
            hp[0] = p0; hp[1] = p1; \
            if (tx == 0) { as2[grow] = vs; ad2[grow] = vd; } \
        } }
    G2OUT(0, acc0) G2OUT(1, acc1) G2OUT(2, acc2) G2OUT(3, acc3)
#undef G2OUT
}

// ---- Layer 2 aggregation: no-max softmax, 4+4 two-batch fp16 gathers, fma_mix --

__global__ __launch_bounds__(256) void agg2_kernel(const __half* __restrict__ h2,
                                                   const float* __restrict__ as2,
                                                   const float* __restrict__ ad2,
                                                   const int* __restrict__ row_ptr,
                                                   const int* __restrict__ src_sorted,
                                                   const float* __restrict__ b2,
                                                   float* __restrict__ out) {
    int n = blockIdx.x * 4 + (threadIdx.x >> 6);
    int lane = threadIdx.x & 63;
    if (n >= N_NODES) return;
    int beg = row_ptr[n], end = row_ptr[n + 1];
    int deg = end - beg;
    float adn = ad2[n];

    int e0 = beg + lane;
    int sidx = 0;
    float p = 0.f;
    if (e0 < end) {
        sidx = src_sorted[e0];
        float t = as2[sidx] + adn;
        t = (t >= 0.f) ? t : NEG_SLOPE * t;
        p = __expf(t);
    }
    float s = p;

    int g  = lane >> 3;       // 8 groups of 8 lanes; one edge per group per round
    int ho = (lane & 7) * 4;  // 4 halves (8B) per lane covers the 32-feature row

    float4 acc = {0.f, 0.f, 0.f, 0.f};
#define ACC2(V, W) { \
        FMAMIX_LO(acc.x, V.x, W); FMAMIX_HI(acc.y, V.x, W); \
        FMAMIX_LO(acc.z, V.y, W); FMAMIX_HI(acc.w, V.y, W); }

#define BATCH2(K0) { \
        float ws0 = __shfl(p, (K0 + 0) * 8 + g, 64); \
        float ws1 = __shfl(p, (K0 + 1) * 8 + g, 64); \
        float ws2 = __shfl(p, (K0 + 2) * 8 + g, 64); \
        float ws3 = __shfl(p, (K0 + 3) * 8 + g, 64); \
        int   ss0 = __shfl(sidx, (K0 + 0) * 8 + g, 64); \
        int   ss1 = __shfl(sidx, (K0 + 1) * 8 + g, 64); \
        int   ss2 = __shfl(sidx, (K0 + 2) * 8 + g, 64); \
        int   ss3 = __shfl(sidx, (K0 + 3) * 8 + g, 64); \
        uint2 v0 = *(const uint2*)&h2[(unsigned)ss0 * OUT_F + ho]; \
        uint2 v1 = *(const uint2*)&h2[(unsigned)ss1 * OUT_F + ho]; \
        uint2 v2 = *(const uint2*)&h2[(unsigned)ss2 * OUT_F + ho]; \
        uint2 v3 = *(const uint2*)&h2[(unsigned)ss3 * OUT_F + ho]; \
        ACC2(v0, ws0) ACC2(v1, ws1) ACC2(v2, ws2) ACC2(v3, ws3) }

    BATCH2(0)
    if (deg > 32) BATCH2(4)
#undef BATCH2

    for (int cb = beg + 64; cb < end; cb += 64) {   // rare deg>64 remainder
        int e = cb + lane;
        float pr = 0.f;
        int sr = 0;
        if (e < end) {
            sr = src_sorted[e];
            float t = as2[sr] + adn;
            t = (t >= 0.f) ? t : NEG_SLOPE * t;
            pr = __expf(t);
            s += pr;
        }
        int cnt = min(64, end - cb);
        int rr = (cnt + 7) >> 3;
        for (int k = 0; k < rr; ++k) {
            float wk = __shfl(pr, k * 8 + g, 64);
            int   sk = __shfl(sr, k * 8 + g, 64);
            uint2 hv = *(const uint2*)&h2[(unsigned)sk * OUT_F + ho];
            ACC2(hv, wk)
        }
    }
#undef ACC2

    s += __shfl_xor(s, 32, 64); s += __shfl_xor(s, 16, 64); s += __shfl_xor(s, 8, 64);
    s += __shfl_xor(s, 4, 64);  s += __shfl_xor(s, 2, 64);  s += __shfl_xor(s, 1, 64);
    float invs = __builtin_amdgcn_rcpf(s);

    acc.x += __shfl_xor(acc.x, 8, 64); acc.x += __shfl_xor(acc.x, 16, 64); acc.x += __shfl_xor(acc.x, 32, 64);
    acc.y += __shfl_xor(acc.y, 8, 64); acc.y += __shfl_xor(acc.y, 16, 64); acc.y += __shfl_xor(acc.y, 32, 64);
    acc.z += __shfl_xor(acc.z, 8, 64); acc.z += __shfl_xor(acc.z, 16, 64); acc.z += __shfl_xor(acc.z, 32, 64);
    acc.w += __shfl_xor(acc.w, 8, 64); acc.w += __shfl_xor(acc.w, 16, 64); acc.w += __shfl_xor(acc.w, 32, 64);

    int fo = (lane & 7) * 4;
    float4 bv = *(const float4*)&b2[fo];
    float4 v;
    v.x = fmaf(acc.x, invs, bv.x); v.y = fmaf(acc.y, invs, bv.y);
    v.z = fmaf(acc.z, invs, bv.z); v.w = fmaf(acc.w, invs, bv.w);

    // row softmax over 32 features; |v| <= ~10 -> no max subtraction needed
    float4 ev;
    ev.x = __expf(v.x); ev.y = __expf(v.y);
    ev.z = __expf(v.z); ev.w = __expf(v.w);
    float ls = ev.x + ev.y + ev.z + ev.w;
    ls += __shfl_xor(ls, 1, 64);
    ls += __shfl_xor(ls, 2, 64);
    ls += __shfl_xor(ls, 4, 64);
    float invl = __builtin_amdgcn_rcpf(ls);
    if (lane < 8) {
        float4 o;
        o.x = ev.x * invl; o.y = ev.y * invl; o.z = ev.z * invl; o.w = ev.w * invl;
        *(float4*)&out[(size_t)n * OUT_F + fo] = o;
    }
}

// ---------------- launch ----------------

extern "C" void kernel_launch(void* const* d_in, const int* in_sizes, int n_in,
                              void* d_out, int out_size, void* d_ws, size_t ws_size,
                              hipStream_t stream) {
    const float* x     = (const float*)d_in[0];
    const int*   ei    = (const int*)d_in[1];
    const float* W1    = (const float*)d_in[2];
    const float* asrc1 = (const float*)d_in[3];
    const float* adst1 = (const float*)d_in[4];
    const float* b1    = (const float*)d_in[5];
    const float* W2    = (const float*)d_in[6];
    const float* asrc2 = (const float*)d_in[7];
    const float* adst2 = (const float*)d_in[8];
    const float* b2    = (const float*)d_in[9];
    float* out = (float*)d_out;

    char* p = (char*)d_ws;
    auto alloc = [&](size_t bytes) {
        char* q = p;
        p += (bytes + 255) & ~size_t(255);
        return q;
    };
    int*    row_ptr     = (int*)   alloc(sizeof(int) * (N_NODES + 1));
    int*    bpart       = (int*)   alloc(sizeof(int) * (size_t)HIST_BLOCKS * NB);
    int*    bucket_base = (int*)   alloc(sizeof(int) * (NB + 1));
    int*    gcursor     = (int*)   alloc(sizeof(int) * NB);
    int*    src_sorted  = (int*)   alloc(sizeof(int) * (size_t)ET);
    __half* h1          = (__half*)alloc(sizeof(__half) * (size_t)N_NODES * HID_F);
    float*  as1         = (float*) alloc(sizeof(float) * N_NODES);
    float*  ad1         = (float*) alloc(sizeof(float) * N_NODES);
    float*  r1          = (float*) alloc(sizeof(float) * (size_t)N_NODES * HID_F);
    __half* h2          = (__half*)alloc(sizeof(__half) * (size_t)N_NODES * OUT_F);
    float*  as2v        = (float*) alloc(sizeof(float) * N_NODES);
    float*  ad2v        = (float*) alloc(sizeof(float) * N_NODES);
    unsigned* staging   = (unsigned*)r1;   // aliases r1; dead before agg1 writes r1

    hipLaunchKernelGGL(histB_kernel, dim3(HIST_BLOCKS), dim3(256), 0, stream, ei, bpart);
    hipLaunchKernelGGL(scanB_kernel, dim3(1), dim3(512), 0, stream,
                       bpart, bucket_base, gcursor, row_ptr);
    hipLaunchKernelGGL(partA_kernel, dim3(BLOCKS_A), dim3(256), 0, stream, ei, gcursor, staging);
    hipLaunchKernelGGL(partB_kernel, dim3(NB), dim3(256), 0, stream,
                       staging, bucket_base, row_ptr, src_sorted);
    hipLaunchKernelGGL(gemm1_kernel, dim3((N_NODES + 63) / 64), dim3(256), 0, stream,
                       x, W1, asrc1, adst1, h1, as1, ad1);
    hipLaunchKernelGGL(agg1_kernel, dim3((N_NODES + 3) / 4), dim3(256), 0, stream,
                       h1, as1, ad1, row_ptr, src_sorted, b1, r1);
    hipLaunchKernelGGL(gemm2_kernel, dim3((N_NODES + 127) / 128), dim3(256), 0, stream,
                       r1, W2, asrc2, adst2, h2, as2v, ad2v);
    hipLaunchKernelGGL(agg2_kernel, dim3((N_NODES + 3) / 4), dim3(256), 0, stream,
                       h2, as2v, ad2v, row_ptr, src_sorted, b2, out);
}